// Round 1
// baseline (1262.891 us; speedup 1.0000x reference)
//
#include <hip/hip_runtime.h>
#include <hip/hip_bf16.h>

#define T_TOK 1024
#define HDIM  1024
#define NEXP  16
#define IDIM  2880
#define GU_COLS (2*IDIM)   // 5760
#define TOPK  4

using short8   = __attribute__((ext_vector_type(8))) short;
using ushort4v = __attribute__((ext_vector_type(4))) unsigned short;
using f32x4    = __attribute__((ext_vector_type(4))) float;

__device__ __forceinline__ unsigned short f2b(float f) {
    union { float f; unsigned u; } x; x.f = f;
    unsigned r = x.u + 0x7FFFu + ((x.u >> 16) & 1u);  // RNE
    return (unsigned short)(r >> 16);
}

// ---------------- Kernel 1: router -----------------------------------------
// One block per token. 16 threads per expert compute the dot, thread 0 does
// top-4 + softmax and appends (token, weight) to per-expert lists.
__global__ __launch_bounds__(256) void router_kernel(
    const float* __restrict__ x, const float* __restrict__ gw,
    const float* __restrict__ gb, float* __restrict__ logits_out,
    int* __restrict__ counts, int* __restrict__ lists, float* __restrict__ wts)
{
    int t = blockIdx.x;
    int tid = threadIdx.x;
    int e = tid >> 4;
    int l16 = tid & 15;
    const float* xr = x + (size_t)t * HDIM;
    const float* wr = gw + (size_t)e * HDIM;
    float p = 0.f;
    for (int h = l16; h < HDIM; h += 16) p += xr[h] * wr[h];
    p += __shfl_xor(p, 8);
    p += __shfl_xor(p, 4);
    p += __shfl_xor(p, 2);
    p += __shfl_xor(p, 1);
    __shared__ float sl[NEXP];
    if (l16 == 0) {
        float v = p + gb[e];
        sl[e] = v;
        logits_out[t * NEXP + e] = v;
    }
    __syncthreads();
    if (tid == 0) {
        float v[NEXP];
#pragma unroll
        for (int i = 0; i < NEXP; ++i) v[i] = sl[i];
        int idx[TOPK]; float tv[TOPK];
        unsigned used = 0;
#pragma unroll
        for (int k = 0; k < TOPK; ++k) {
            float best = -__builtin_inff(); int bi = 0;
#pragma unroll
            for (int i = 0; i < NEXP; ++i)
                if (!((used >> i) & 1u) && v[i] > best) { best = v[i]; bi = i; }
            used |= 1u << bi; idx[k] = bi; tv[k] = best;
        }
        float m = tv[0];           // largest
        float ex[TOPK], s = 0.f;
#pragma unroll
        for (int k = 0; k < TOPK; ++k) { ex[k] = expf(tv[k] - m); s += ex[k]; }
#pragma unroll
        for (int k = 0; k < TOPK; ++k) {
            float w = ex[k] / s;
            int slot = atomicAdd(&counts[idx[k]], 1);
            lists[idx[k] * T_TOK + slot] = t;
            wts[idx[k] * T_TOK + slot] = w;
        }
    }
}

// ---------------- Kernel 2: exclusive prefix sum of counts ------------------
__global__ void offsets_kernel(const int* __restrict__ counts, int* __restrict__ offsets)
{
    if (threadIdx.x == 0) {
        int o = 0;
        for (int e = 0; e < NEXP; ++e) { offsets[e] = o; o += counts[e]; }
        offsets[NEXP] = o;
    }
}

// ---------------- Kernel 3: gate_up GEMM + silu fuse ------------------------
// Tile: BM=64 gathered tokens x BN=64 weight cols (32 gate + 32 matching up).
// K = HDIM, BK = 64. 4 waves, each a 32x32 quadrant of 16x16x32 bf16 MFMAs.
// Epilogue: inter[row][nt*32+c] = silu(gate+bg)*(up+bu) in bf16.
#define NT2 (IDIM/32)    // 90
#define MT2 (T_TOK/64)   // 16
#define LDA 72           // padded ushort stride (144B): ds_read_b128 ~2-way

__global__ __launch_bounds__(256) void gu_kernel(
    const float* __restrict__ x, const float* __restrict__ gup,
    const float* __restrict__ gub, const int* __restrict__ counts,
    const int* __restrict__ offsets, const int* __restrict__ lists,
    unsigned short* __restrict__ inter)
{
    int bid = blockIdx.x;
    int mt = bid & 15;
    int tmp = bid >> 4;
    int nt = tmp % NT2;
    int e  = tmp / NT2;
    int ne = counts[e];
    if (mt * 64 >= ne) return;

    int tid = threadIdx.x;
    int wave = tid >> 6, lane = tid & 63;
    int wm = wave >> 1, wn = wave & 1;
    int l16 = lane & 15, lq = lane >> 4;

    __shared__ unsigned short As[64][LDA];
    __shared__ unsigned short Bs[64][LDA];
    __shared__ float Cs[64][65];
    __shared__ int tokid[64];

    if (tid < 64) {
        int slot = mt * 64 + tid;
        tokid[tid] = (slot < ne) ? lists[e * T_TOK + slot] : -1;
    }
    __syncthreads();

    f32x4 acc00 = {0,0,0,0}, acc01 = {0,0,0,0}, acc10 = {0,0,0,0}, acc11 = {0,0,0,0};

    const float* gup_e = gup + (size_t)e * HDIM * GU_COLS;

    int ar = tid >> 2;            // A row 0..63
    int aq = tid & 3;             // 16-float quarter
    int atok = tokid[ar];
    const float* asrc = x + (size_t)(atok >= 0 ? atok : 0) * HDIM + aq * 16;

    int fq = tid & 15;            // B micro col group
    int kq = tid >> 4;            // B micro k group 0..15
    int f0 = fq * 4;
    int gcol = (f0 < 32) ? (nt * 32 + f0) : (IDIM + nt * 32 + (f0 - 32));

    for (int kk = 0; kk < HDIM; kk += 64) {
        __syncthreads();
        // ---- stage A (gathered tokens, fp32 -> bf16) ----
        {
            const float4* s4 = (const float4*)(asrc + kk);
#pragma unroll
            for (int u = 0; u < 4; ++u) {
                float4 v = (atok >= 0) ? s4[u] : make_float4(0.f, 0.f, 0.f, 0.f);
                ushort4v b; b.x = f2b(v.x); b.y = f2b(v.y); b.z = f2b(v.z); b.w = f2b(v.w);
                *(ushort4v*)&As[ar][aq * 16 + u * 4] = b;
            }
        }
        // ---- stage B (K-strided weights, 4x4 micro-transpose fp32->bf16) ----
        {
            const float* src = gup_e + (size_t)(kk + kq * 4) * GU_COLS + gcol;
            float4 r0 = *(const float4*)(src);
            float4 r1 = *(const float4*)(src + GU_COLS);
            float4 r2 = *(const float4*)(src + 2 * GU_COLS);
            float4 r3 = *(const float4*)(src + 3 * GU_COLS);
            ushort4v b;
            b.x=f2b(r0.x); b.y=f2b(r1.x); b.z=f2b(r2.x); b.w=f2b(r3.x);
            *(ushort4v*)&Bs[f0 + 0][kq * 4] = b;
            b.x=f2b(r0.y); b.y=f2b(r1.y); b.z=f2b(r2.y); b.w=f2b(r3.y);
            *(ushort4v*)&Bs[f0 + 1][kq * 4] = b;
            b.x=f2b(r0.z); b.y=f2b(r1.z); b.z=f2b(r2.z); b.w=f2b(r3.z);
            *(ushort4v*)&Bs[f0 + 2][kq * 4] = b;
            b.x=f2b(r0.w); b.y=f2b(r1.w); b.z=f2b(r2.w); b.w=f2b(r3.w);
            *(ushort4v*)&Bs[f0 + 3][kq * 4] = b;
        }
        __syncthreads();
        // ---- MFMA: 2 k-steps of 32 ----
#pragma unroll
        for (int ks = 0; ks < 2; ++ks) {
            short8 a0 = *(const short8*)&As[wm * 32 +  0 + l16][ks * 32 + lq * 8];
            short8 a1 = *(const short8*)&As[wm * 32 + 16 + l16][ks * 32 + lq * 8];
            short8 b0 = *(const short8*)&Bs[wn * 32 +  0 + l16][ks * 32 + lq * 8];
            short8 b1 = *(const short8*)&Bs[wn * 32 + 16 + l16][ks * 32 + lq * 8];
            acc00 = __builtin_amdgcn_mfma_f32_16x16x32_bf16(a0, b0, acc00, 0, 0, 0);
            acc01 = __builtin_amdgcn_mfma_f32_16x16x32_bf16(a0, b1, acc01, 0, 0, 0);
            acc10 = __builtin_amdgcn_mfma_f32_16x16x32_bf16(a1, b0, acc10, 0, 0, 0);
            acc11 = __builtin_amdgcn_mfma_f32_16x16x32_bf16(a1, b1, acc11, 0, 0, 0);
        }
    }

    // ---- epilogue: stage C, pair gate/up across waves, silu, write bf16 ----
#pragma unroll
    for (int r = 0; r < 4; ++r) {
        Cs[wm * 32 +  0 + lq * 4 + r][wn * 32 +  0 + l16] = acc00[r];
        Cs[wm * 32 +  0 + lq * 4 + r][wn * 32 + 16 + l16] = acc01[r];
        Cs[wm * 32 + 16 + lq * 4 + r][wn * 32 +  0 + l16] = acc10[r];
        Cs[wm * 32 + 16 + lq * 4 + r][wn * 32 + 16 + l16] = acc11[r];
    }
    __syncthreads();

    int m = tid >> 2;
    int cb = (tid & 3) * 8;       // 0..24 (gate half)
    int slotg = mt * 64 + m;
    if (slotg < ne) {
        int row = offsets[e] + slotg;
        const float* bg = gub + (size_t)e * GU_COLS + nt * 32;
        unsigned short ob[8];
#pragma unroll
        for (int q = 0; q < 8; ++q) {
            int c = cb + q;
            float g = Cs[m][c]      + bg[c];
            float u = Cs[m][c + 32] + bg[IDIM + c];
            float sg = g / (1.f + expf(-g));   // silu
            ob[q] = f2b(sg * u);
        }
        unsigned short* dst = inter + (size_t)row * IDIM + nt * 32 + cb;
        ushort4v v0 = {ob[0], ob[1], ob[2], ob[3]};
        ushort4v v1 = {ob[4], ob[5], ob[6], ob[7]};
        *(ushort4v*)dst = v0;
        *(ushort4v*)(dst + 4) = v1;
    }
}

// ---------------- Kernel 4: down GEMM + weighted scatter-add ---------------
#define NT3 (HDIM/64)    // 16
#define MT3 (T_TOK/64)   // 16

__global__ __launch_bounds__(256) void down_kernel(
    const unsigned short* __restrict__ inter, const float* __restrict__ dw,
    const float* __restrict__ db, const int* __restrict__ counts,
    const int* __restrict__ offsets, const int* __restrict__ lists,
    const float* __restrict__ wts, float* __restrict__ out)
{
    int bid = blockIdx.x;
    int mt = bid & 15;
    int tmp = bid >> 4;
    int nt = tmp & 15;
    int e  = tmp >> 4;
    int ne = counts[e];
    if (mt * 64 >= ne) return;

    int tid = threadIdx.x;
    int wave = tid >> 6, lane = tid & 63;
    int wm = wave >> 1, wn = wave & 1;
    int l16 = lane & 15, lq = lane >> 4;

    __shared__ unsigned short As[64][LDA];
    __shared__ unsigned short Bs[64][LDA];
    __shared__ int tokid[64];
    __shared__ float twt[64];

    if (tid < 64) {
        int slot = mt * 64 + tid;
        tokid[tid] = (slot < ne) ? lists[e * T_TOK + slot] : -1;
        twt[tid]   = (slot < ne) ? wts[e * T_TOK + slot] : 0.f;
    }
    int off = offsets[e];
    __syncthreads();

    f32x4 acc00 = {0,0,0,0}, acc01 = {0,0,0,0}, acc10 = {0,0,0,0}, acc11 = {0,0,0,0};

    const float* dw_e = dw + (size_t)e * IDIM * HDIM;

    int ar = tid >> 2, aq = tid & 3;
    bool avalid = (mt * 64 + ar) < ne;
    const unsigned short* asrc = inter + (size_t)(off + mt * 64 + ar) * IDIM + aq * 16;

    int fq = tid & 15, kq = tid >> 4;
    int f0 = fq * 4;
    int gcol = nt * 64 + f0;

    for (int kk = 0; kk < IDIM; kk += 64) {
        __syncthreads();
        // ---- stage A (bf16 inter rows, contiguous) ----
        {
            short8 v0 = {0,0,0,0,0,0,0,0}, v1 = {0,0,0,0,0,0,0,0};
            if (avalid) {
                const short8* s = (const short8*)(asrc + kk);
                v0 = s[0]; v1 = s[1];
            }
            *(short8*)&As[ar][aq * 16]     = v0;
            *(short8*)&As[ar][aq * 16 + 8] = v1;
        }
        // ---- stage B (down weights, 4x4 micro-transpose fp32->bf16) ----
        {
            const float* src = dw_e + (size_t)(kk + kq * 4) * HDIM + gcol;
            float4 r0 = *(const float4*)(src);
            float4 r1 = *(const float4*)(src + HDIM);
            float4 r2 = *(const float4*)(src + 2 * HDIM);
            float4 r3 = *(const float4*)(src + 3 * HDIM);
            ushort4v b;
            b.x=f2b(r0.x); b.y=f2b(r1.x); b.z=f2b(r2.x); b.w=f2b(r3.x);
            *(ushort4v*)&Bs[f0 + 0][kq * 4] = b;
            b.x=f2b(r0.y); b.y=f2b(r1.y); b.z=f2b(r2.y); b.w=f2b(r3.y);
            *(ushort4v*)&Bs[f0 + 1][kq * 4] = b;
            b.x=f2b(r0.z); b.y=f2b(r1.z); b.z=f2b(r2.z); b.w=f2b(r3.z);
            *(ushort4v*)&Bs[f0 + 2][kq * 4] = b;
            b.x=f2b(r0.w); b.y=f2b(r1.w); b.z=f2b(r2.w); b.w=f2b(r3.w);
            *(ushort4v*)&Bs[f0 + 3][kq * 4] = b;
        }
        __syncthreads();
#pragma unroll
        for (int ks = 0; ks < 2; ++ks) {
            short8 a0 = *(const short8*)&As[wm * 32 +  0 + l16][ks * 32 + lq * 8];
            short8 a1 = *(const short8*)&As[wm * 32 + 16 + l16][ks * 32 + lq * 8];
            short8 b0 = *(const short8*)&Bs[wn * 32 +  0 + l16][ks * 32 + lq * 8];
            short8 b1 = *(const short8*)&Bs[wn * 32 + 16 + l16][ks * 32 + lq * 8];
            acc00 = __builtin_amdgcn_mfma_f32_16x16x32_bf16(a0, b0, acc00, 0, 0, 0);
            acc01 = __builtin_amdgcn_mfma_f32_16x16x32_bf16(a0, b1, acc01, 0, 0, 0);
            acc10 = __builtin_amdgcn_mfma_f32_16x16x32_bf16(a1, b0, acc10, 0, 0, 0);
            acc11 = __builtin_amdgcn_mfma_f32_16x16x32_bf16(a1, b1, acc11, 0, 0, 0);
        }
    }

    // ---- epilogue: w * (acc + bias) scatter-add into out ----
    const float* db_e = db + (size_t)e * HDIM + nt * 64 + wn * 32;
#pragma unroll
    for (int j = 0; j < 2; ++j) {
        int h = nt * 64 + wn * 32 + j * 16 + l16;
        float bias = db_e[j * 16 + l16];
        const f32x4* accj0 = (j == 0) ? &acc00 : &acc01;
        const f32x4* accj1 = (j == 0) ? &acc10 : &acc11;
#pragma unroll
        for (int i = 0; i < 2; ++i) {
            const f32x4& a = (i == 0) ? *accj0 : *accj1;
#pragma unroll
            for (int r = 0; r < 4; ++r) {
                int sl = wm * 32 + i * 16 + lq * 4 + r;
                int tk = tokid[sl];
                if (tk >= 0) {
                    atomicAdd(out + (size_t)tk * HDIM + h, twt[sl] * (a[r] + bias));
                }
            }
        }
    }
}

// ---------------------------------------------------------------------------
extern "C" void kernel_launch(void* const* d_in, const int* in_sizes, int n_in,
                              void* d_out, int out_size, void* d_ws, size_t ws_size,
                              hipStream_t stream)
{
    const float* x   = (const float*)d_in[0];   // (1,1024,1024)
    const float* gw  = (const float*)d_in[1];   // (16,1024)
    const float* gb  = (const float*)d_in[2];   // (16,)
    const float* gup = (const float*)d_in[3];   // (16,1024,5760)
    const float* gub = (const float*)d_in[4];   // (16,5760)
    const float* dw  = (const float*)d_in[5];   // (16,2880,1024)
    const float* db  = (const float*)d_in[6];   // (16,1024)

    float* out        = (float*)d_out;              // 1048576 floats
    float* logits_out = out + (size_t)T_TOK * HDIM; // 16384 floats

    char* ws = (char*)d_ws;
    int*   counts  = (int*)ws;                         // 16 ints
    int*   offsets = (int*)(ws + 64);                  // 17 ints
    int*   lists   = (int*)(ws + 256);                 // 16*1024 ints
    float* wts     = (float*)(ws + 256 + 65536);       // 16*1024 floats
    unsigned short* inter = (unsigned short*)(ws + 256 + 65536 + 65536); // 4096*2880 bf16

    hipMemsetAsync(out, 0, (size_t)T_TOK * HDIM * sizeof(float), stream);
    hipMemsetAsync(counts, 0, 64, stream);

    router_kernel<<<T_TOK, 256, 0, stream>>>(x, gw, gb, logits_out, counts, lists, wts);
    offsets_kernel<<<1, 64, 0, stream>>>(counts, offsets);
    gu_kernel<<<NEXP * NT2 * MT2, 256, 0, stream>>>(x, gup, gub, counts, offsets, lists, inter);
    down_kernel<<<NEXP * NT3 * MT3, 256, 0, stream>>>(inter, dw, db, counts, offsets, lists, wts, out);
}

// Round 2
// 909.330 us; speedup vs baseline: 1.3888x; 1.3888x over previous
//
#include <hip/hip_runtime.h>
#include <hip/hip_bf16.h>
#include <stdint.h>

#define T_TOK 1024
#define HDIM  1024
#define NEXP  16
#define IDIM  2880
#define GU_COLS (2*IDIM)   // 5760
#define TOPK  4

using short8   = __attribute__((ext_vector_type(8))) short;
using ushort4v = __attribute__((ext_vector_type(4))) unsigned short;
using f32x4    = __attribute__((ext_vector_type(4))) float;

__device__ __forceinline__ unsigned short f2b(float f) {
    union { float f; unsigned u; } x; x.f = f;
    unsigned r = x.u + 0x7FFFu + ((x.u >> 16) & 1u);  // RNE
    return (unsigned short)(r >> 16);
}

typedef const __attribute__((address_space(1))) unsigned int* gas1_t;
typedef __attribute__((address_space(3))) unsigned int* las3_t;
__device__ __forceinline__ void gload16(const void* g, void* l) {
    __builtin_amdgcn_global_load_lds((gas1_t)g, (las3_t)l, 16, 0, 0);
}

// ---------------- Kernel 0: fp32 -> bf16 transpose-convert ------------------
// src: [E][R][C] fp32, dst: [E][C][R] bf16. 64x64 tiles, 256 threads.
__global__ __launch_bounds__(256) void convert_tr_kernel(
    const float* __restrict__ src, unsigned short* __restrict__ dst,
    int R, int C, int nRB, int nCB)
{
    int bid = blockIdx.x;
    int e   = bid / (nRB * nCB);
    int rem = bid % (nRB * nCB);
    int rb  = rem / nCB, cb = rem % nCB;
    const float* s = src + (size_t)e * R * C + (size_t)(rb * 64) * C + cb * 64;
    unsigned short* d = dst + (size_t)e * R * C + (size_t)(cb * 64) * R + rb * 64;

    __shared__ unsigned short L[64][66];   // pad 66: write conflicts ~2-way
    int tid = threadIdx.x;
    int rr = tid >> 4;          // 0..15
    int c0 = (tid & 15) * 4;
#pragma unroll
    for (int sh = 0; sh < 4; ++sh) {
        int r = sh * 16 + rr;
        float4 v = *(const float4*)(s + (size_t)r * C + c0);
        L[c0 + 0][r] = f2b(v.x); L[c0 + 1][r] = f2b(v.y);
        L[c0 + 2][r] = f2b(v.z); L[c0 + 3][r] = f2b(v.w);
    }
    __syncthreads();
    int h0 = (tid & 7) * 8;
#pragma unroll
    for (int sh = 0; sh < 2; ++sh) {
        int c = sh * 32 + (tid >> 3);
        unsigned short t0[8];
#pragma unroll
        for (int j = 0; j < 8; ++j) t0[j] = L[c][h0 + j];
        ushort4v v0 = {t0[0], t0[1], t0[2], t0[3]};
        ushort4v v1 = {t0[4], t0[5], t0[6], t0[7]};
        *(ushort4v*)(d + (size_t)c * R + h0)     = v0;
        *(ushort4v*)(d + (size_t)c * R + h0 + 4) = v1;
    }
}

// ---------------- Kernel 1: router + x->bf16 --------------------------------
__global__ __launch_bounds__(256) void router_kernel(
    const float* __restrict__ x, const float* __restrict__ gw,
    const float* __restrict__ gb, float* __restrict__ logits_out,
    int* __restrict__ counts, int* __restrict__ lists, float* __restrict__ wts,
    unsigned short* __restrict__ xb)
{
    int t = blockIdx.x;
    int tid = threadIdx.x;
    const float* xr = x + (size_t)t * HDIM;
    // x -> bf16
    {
        float4 v = *(const float4*)(xr + tid * 4);
        ushort4v b; b.x = f2b(v.x); b.y = f2b(v.y); b.z = f2b(v.z); b.w = f2b(v.w);
        *(ushort4v*)(xb + (size_t)t * HDIM + tid * 4) = b;
    }
    int e = tid >> 4;
    int l16 = tid & 15;
    const float* wr = gw + (size_t)e * HDIM;
    float p = 0.f;
    for (int h = l16; h < HDIM; h += 16) p += xr[h] * wr[h];
    p += __shfl_xor(p, 8);
    p += __shfl_xor(p, 4);
    p += __shfl_xor(p, 2);
    p += __shfl_xor(p, 1);
    __shared__ float sl[NEXP];
    if (l16 == 0) {
        float v = p + gb[e];
        sl[e] = v;
        logits_out[t * NEXP + e] = v;
    }
    __syncthreads();
    if (tid == 0) {
        float v[NEXP];
#pragma unroll
        for (int i = 0; i < NEXP; ++i) v[i] = sl[i];
        int idx[TOPK]; float tv[TOPK];
        unsigned used = 0;
#pragma unroll
        for (int k = 0; k < TOPK; ++k) {
            float best = -__builtin_inff(); int bi = 0;
#pragma unroll
            for (int i = 0; i < NEXP; ++i)
                if (!((used >> i) & 1u) && v[i] > best) { best = v[i]; bi = i; }
            used |= 1u << bi; idx[k] = bi; tv[k] = best;
        }
        float m = tv[0];
        float ex[TOPK], s = 0.f;
#pragma unroll
        for (int k = 0; k < TOPK; ++k) { ex[k] = expf(tv[k] - m); s += ex[k]; }
#pragma unroll
        for (int k = 0; k < TOPK; ++k) {
            float w = ex[k] / s;
            int slot = atomicAdd(&counts[idx[k]], 1);
            lists[idx[k] * T_TOK + slot] = t;
            wts[idx[k] * T_TOK + slot] = w;
        }
    }
}

// ---------------- Kernel 2: exclusive prefix sum ---------------------------
__global__ void offsets_kernel(const int* __restrict__ counts, int* __restrict__ offsets)
{
    if (threadIdx.x == 0) {
        int o = 0;
        for (int e = 0; e < NEXP; ++e) { offsets[e] = o; o += counts[e]; }
        offsets[NEXP] = o;
    }
}

// ---------------- Kernel 3: gate_up GEMM + silu ----------------------------
// BM=128 gathered tokens, B rows = 64 gate cols + 64 up cols (transposed bf16
// weights, K-contiguous), BK=64, 4 waves (2x2), wave tile 64x64.
__global__ __launch_bounds__(256) void gu_kernel(
    const unsigned short* __restrict__ xb, const unsigned short* __restrict__ gupb,
    const float* __restrict__ gub, const int* __restrict__ counts,
    const int* __restrict__ offsets, const int* __restrict__ lists,
    unsigned short* __restrict__ inter)
{
    int bid = blockIdx.x;
    int mt = bid & 7;
    int t2 = bid >> 3;
    int nt = t2 % 45;
    int e  = t2 / 45;
    int ne = counts[e];
    if (mt * 128 >= ne) return;

    int tid = threadIdx.x;
    int wave = tid >> 6, lane = tid & 63;
    int l16 = lane & 15, lq = lane >> 4;
    int wm = wave >> 1, wn = wave & 1;

    __shared__ int tokid[128];
    __shared__ unsigned short sm[16384];   // As[0..8191], Bs[8192..16383]; reused as float Cs
    unsigned short* As = sm;
    unsigned short* Bs = sm + 8192;

    if (tid < 128) {
        int slot = mt * 128 + tid;
        tokid[tid] = (slot < ne) ? lists[e * T_TOK + slot] : lists[e * T_TOK];
    }
    __syncthreads();

    int cE = (tid & 7) * 8;                 // element offset in 64-wide K chunk
    const unsigned short* gup_e = gupb + (size_t)e * GU_COLS * HDIM;
    const unsigned short* ab[4];
    const unsigned short* bb[4];
#pragma unroll
    for (int s = 0; s < 4; ++s) {
        int row = s * 32 + (tid >> 3);
        ab[s] = xb + (size_t)tokid[row] * HDIM + cE;
        int n = (row < 64) ? (nt * 64 + row) : (IDIM + nt * 64 + (row - 64));
        bb[s] = gup_e + (size_t)n * HDIM + cE;
    }

    f32x4 acc[4][4];
#pragma unroll
    for (int m = 0; m < 4; ++m)
#pragma unroll
        for (int n = 0; n < 4; ++n) acc[m][n] = (f32x4){0.f, 0.f, 0.f, 0.f};

    for (int kk = 0; kk < HDIM; kk += 64) {
        __syncthreads();
#pragma unroll
        for (int s = 0; s < 4; ++s) {
            gload16(ab[s] + kk, As + s * 2048 + tid * 8);
            gload16(bb[s] + kk, Bs + s * 2048 + tid * 8);
        }
        __syncthreads();
#pragma unroll
        for (int ks = 0; ks < 2; ++ks) {
            short8 a[4], b[4];
#pragma unroll
            for (int m = 0; m < 4; ++m)
                a[m] = *(const short8*)&As[(wm * 64 + m * 16 + l16) * 64 + ks * 32 + lq * 8];
#pragma unroll
            for (int n = 0; n < 4; ++n)
                b[n] = *(const short8*)&Bs[(wn * 64 + n * 16 + l16) * 64 + ks * 32 + lq * 8];
#pragma unroll
            for (int m = 0; m < 4; ++m)
#pragma unroll
                for (int n = 0; n < 4; ++n)
                    acc[m][n] = __builtin_amdgcn_mfma_f32_16x16x32_bf16(a[m], b[n], acc[m][n], 0, 0, 0);
        }
    }

    // epilogue: wn=1 (up) stages to LDS, wn=0 (gate) fuses silu and stores
    __syncthreads();
    float* Cs = (float*)sm;                 // 128 x 64 fp32 = 32 KB
    if (wn == 1) {
#pragma unroll
        for (int m = 0; m < 4; ++m)
#pragma unroll
            for (int n = 0; n < 4; ++n)
#pragma unroll
                for (int r = 0; r < 4; ++r)
                    Cs[(wm * 64 + m * 16 + lq * 4 + r) * 64 + n * 16 + l16] = acc[m][n][r];
    }
    __syncthreads();
    if (wn == 0) {
        int off = offsets[e];
        const float* gbe = gub + (size_t)e * GU_COLS;
#pragma unroll
        for (int n = 0; n < 4; ++n) {
            int col = n * 16 + l16;
            float bg = gbe[nt * 64 + col];
            float bu = gbe[IDIM + nt * 64 + col];
#pragma unroll
            for (int m = 0; m < 4; ++m)
#pragma unroll
                for (int r = 0; r < 4; ++r) {
                    int row = wm * 64 + m * 16 + lq * 4 + r;
                    int slot = mt * 128 + row;
                    if (slot < ne) {
                        float g = acc[m][n][r] + bg;
                        float u = Cs[row * 64 + col] + bu;
                        float sg = g / (1.f + expf(-g));
                        inter[(size_t)(off + slot) * IDIM + nt * 64 + col] = f2b(sg * u);
                    }
                }
        }
    }
}

// ---------------- Kernel 4: down GEMM + weighted scatter-add ---------------
// BM=64 slots, BN=128 h-cols (transposed bf16 dw), BK=64, 4 waves (2x2),
// wave tile 32x64.
__global__ __launch_bounds__(256) void down_kernel(
    const unsigned short* __restrict__ inter, const unsigned short* __restrict__ dwb,
    const float* __restrict__ db, const int* __restrict__ counts,
    const int* __restrict__ offsets, const int* __restrict__ lists,
    const float* __restrict__ wts, float* __restrict__ out)
{
    int bid = blockIdx.x;
    int mt = bid & 15;
    int t2 = bid >> 4;
    int nt = t2 & 7;
    int e  = t2 >> 3;
    int ne = counts[e];
    if (mt * 64 >= ne) return;

    int tid = threadIdx.x;
    int wave = tid >> 6, lane = tid & 63;
    int l16 = lane & 15, lq = lane >> 4;
    int wm = wave >> 1, wn = wave & 1;

    __shared__ int tokid[64];
    __shared__ float twt[64];
    __shared__ unsigned short As[64 * 64];    // 8 KB
    __shared__ unsigned short Bs[128 * 64];   // 16 KB

    int off = offsets[e];
    if (tid < 64) {
        int slot = mt * 64 + tid;
        tokid[tid] = (slot < ne) ? lists[e * T_TOK + slot] : -1;
        twt[tid]   = (slot < ne) ? wts[e * T_TOK + slot] : 0.f;
    }
    __syncthreads();

    int cE = (tid & 7) * 8;
    const unsigned short* ab[2];
    const unsigned short* bb[4];
    const unsigned short* dw_e = dwb + (size_t)e * HDIM * IDIM;
#pragma unroll
    for (int s = 0; s < 2; ++s) {
        int row = s * 32 + (tid >> 3);
        int slotr = mt * 64 + row; if (slotr >= ne) slotr = ne - 1;
        ab[s] = inter + (size_t)(off + slotr) * IDIM + cE;
    }
#pragma unroll
    for (int s = 0; s < 4; ++s) {
        int h = nt * 128 + s * 32 + (tid >> 3);
        bb[s] = dw_e + (size_t)h * IDIM + cE;
    }

    f32x4 acc[2][4];
#pragma unroll
    for (int m = 0; m < 2; ++m)
#pragma unroll
        for (int n = 0; n < 4; ++n) acc[m][n] = (f32x4){0.f, 0.f, 0.f, 0.f};

    for (int kk = 0; kk < IDIM; kk += 64) {
        __syncthreads();
#pragma unroll
        for (int s = 0; s < 2; ++s)
            gload16(ab[s] + kk, As + s * 2048 + tid * 8);
#pragma unroll
        for (int s = 0; s < 4; ++s)
            gload16(bb[s] + kk, Bs + s * 2048 + tid * 8);
        __syncthreads();
#pragma unroll
        for (int ks = 0; ks < 2; ++ks) {
            short8 a[2], b[4];
#pragma unroll
            for (int m = 0; m < 2; ++m)
                a[m] = *(const short8*)&As[(wm * 32 + m * 16 + l16) * 64 + ks * 32 + lq * 8];
#pragma unroll
            for (int n = 0; n < 4; ++n)
                b[n] = *(const short8*)&Bs[(wn * 64 + n * 16 + l16) * 64 + ks * 32 + lq * 8];
#pragma unroll
            for (int m = 0; m < 2; ++m)
#pragma unroll
                for (int n = 0; n < 4; ++n)
                    acc[m][n] = __builtin_amdgcn_mfma_f32_16x16x32_bf16(a[m], b[n], acc[m][n], 0, 0, 0);
        }
    }

    const float* db_e = db + (size_t)e * HDIM;
#pragma unroll
    for (int n = 0; n < 4; ++n) {
        int h = nt * 128 + wn * 64 + n * 16 + l16;
        float bias = db_e[h];
#pragma unroll
        for (int m = 0; m < 2; ++m)
#pragma unroll
            for (int r = 0; r < 4; ++r) {
                int slot = wm * 32 + m * 16 + lq * 4 + r;
                int tk = tokid[slot];
                if (tk >= 0)
                    atomicAdd(out + (size_t)tk * HDIM + h, twt[slot] * (acc[m][n][r] + bias));
            }
    }
}

// ---------------------------------------------------------------------------
extern "C" void kernel_launch(void* const* d_in, const int* in_sizes, int n_in,
                              void* d_out, int out_size, void* d_ws, size_t ws_size,
                              hipStream_t stream)
{
    const float* x   = (const float*)d_in[0];
    const float* gw  = (const float*)d_in[1];
    const float* gb  = (const float*)d_in[2];
    const float* gup = (const float*)d_in[3];
    const float* dw  = (const float*)d_in[5];
    const float* gub = (const float*)d_in[4];
    const float* db  = (const float*)d_in[6];

    float* out        = (float*)d_out;
    float* logits_out = out + (size_t)T_TOK * HDIM;

    char* ws = (char*)d_ws;
    int*   counts  = (int*)(ws + 0);
    int*   offsets = (int*)(ws + 256);
    int*   lists   = (int*)(ws + 512);                       // 64 KB
    float* wts     = (float*)(ws + 512 + 65536);             // 64 KB
    unsigned short* xb    = (unsigned short*)(ws + 131584);  // 2 MB
    unsigned short* inter = (unsigned short*)(ws + 2228736); // 23.6 MB
    unsigned short* gupb  = (unsigned short*)(ws + 25821696);// 188.7 MB
    unsigned short* dwb   = (unsigned short*)(ws + 214565376);// 94.4 MB
    // total ws use ~309 MB

    hipMemsetAsync(out, 0, (size_t)T_TOK * HDIM * sizeof(float), stream);
    hipMemsetAsync(counts, 0, 64, stream);

    convert_tr_kernel<<<NEXP * 16 * 90, 256, 0, stream>>>(gup, gupb, HDIM, GU_COLS, 16, 90);
    convert_tr_kernel<<<NEXP * 45 * 16, 256, 0, stream>>>(dw,  dwb,  IDIM, HDIM,    45, 16);
    router_kernel<<<T_TOK, 256, 0, stream>>>(x, gw, gb, logits_out, counts, lists, wts, xb);
    offsets_kernel<<<1, 64, 0, stream>>>(counts, offsets);
    gu_kernel<<<NEXP * 45 * 8, 256, 0, stream>>>(xb, gupb, gub, counts, offsets, lists, inter);
    down_kernel<<<NEXP * 8 * 16, 256, 0, stream>>>(inter, dwb, db, counts, offsets, lists, wts, out);
}

// Round 3
// 430.800 us; speedup vs baseline: 2.9315x; 2.1108x over previous
//
#include <hip/hip_runtime.h>
#include <hip/hip_bf16.h>
#include <stdint.h>

#define T_TOK 1024
#define HDIM  1024
#define NEXP  16
#define IDIM  2880
#define GU_COLS (2*IDIM)   // 5760
#define TOPK  4

using short8   = __attribute__((ext_vector_type(8))) short;
using ushort4v = __attribute__((ext_vector_type(4))) unsigned short;
using f32x4    = __attribute__((ext_vector_type(4))) float;

__device__ __forceinline__ unsigned short f2b(float f) {
    union { float f; unsigned u; } x; x.f = f;
    unsigned r = x.u + 0x7FFFu + ((x.u >> 16) & 1u);  // RNE
    return (unsigned short)(r >> 16);
}

typedef const __attribute__((address_space(1))) unsigned int* gas1_t;
typedef __attribute__((address_space(3))) unsigned int* las3_t;
__device__ __forceinline__ void gload16(const void* g, void* l) {
    __builtin_amdgcn_global_load_lds((gas1_t)g, (las3_t)l, 16, 0, 0);
}

// ---------------- Kernel 0: fp32 -> bf16 transpose-convert ------------------
__global__ __launch_bounds__(256) void convert_tr_kernel(
    const float* __restrict__ src, unsigned short* __restrict__ dst,
    int R, int C, int nRB, int nCB)
{
    int bid = blockIdx.x;
    int e   = bid / (nRB * nCB);
    int rem = bid % (nRB * nCB);
    int rb  = rem / nCB, cb = rem % nCB;
    const float* s = src + (size_t)e * R * C + (size_t)(rb * 64) * C + cb * 64;
    unsigned short* d = dst + (size_t)e * R * C + (size_t)(cb * 64) * R + rb * 64;

    __shared__ unsigned short L[64][66];
    int tid = threadIdx.x;
    int rr = tid >> 4;
    int c0 = (tid & 15) * 4;
#pragma unroll
    for (int sh = 0; sh < 4; ++sh) {
        int r = sh * 16 + rr;
        float4 v = *(const float4*)(s + (size_t)r * C + c0);
        L[c0 + 0][r] = f2b(v.x); L[c0 + 1][r] = f2b(v.y);
        L[c0 + 2][r] = f2b(v.z); L[c0 + 3][r] = f2b(v.w);
    }
    __syncthreads();
    int h0 = (tid & 7) * 8;
#pragma unroll
    for (int sh = 0; sh < 2; ++sh) {
        int c = sh * 32 + (tid >> 3);
        unsigned short t0[8];
#pragma unroll
        for (int j = 0; j < 8; ++j) t0[j] = L[c][h0 + j];
        ushort4v v0 = {t0[0], t0[1], t0[2], t0[3]};
        ushort4v v1 = {t0[4], t0[5], t0[6], t0[7]};
        *(ushort4v*)(d + (size_t)c * R + h0)     = v0;
        *(ushort4v*)(d + (size_t)c * R + h0 + 4) = v1;
    }
}

// ---------------- Kernel 1: router + x->bf16 --------------------------------
__global__ __launch_bounds__(256) void router_kernel(
    const float* __restrict__ x, const float* __restrict__ gw,
    const float* __restrict__ gb, float* __restrict__ logits_out,
    int* __restrict__ counts, int* __restrict__ lists, float* __restrict__ wts,
    unsigned short* __restrict__ xb)
{
    int t = blockIdx.x;
    int tid = threadIdx.x;
    const float* xr = x + (size_t)t * HDIM;
    {
        float4 v = *(const float4*)(xr + tid * 4);
        ushort4v b; b.x = f2b(v.x); b.y = f2b(v.y); b.z = f2b(v.z); b.w = f2b(v.w);
        *(ushort4v*)(xb + (size_t)t * HDIM + tid * 4) = b;
    }
    int e = tid >> 4;
    int l16 = tid & 15;
    const float* wr = gw + (size_t)e * HDIM;
    float p = 0.f;
    for (int h = l16; h < HDIM; h += 16) p += xr[h] * wr[h];
    p += __shfl_xor(p, 8);
    p += __shfl_xor(p, 4);
    p += __shfl_xor(p, 2);
    p += __shfl_xor(p, 1);
    __shared__ float sl[NEXP];
    if (l16 == 0) {
        float v = p + gb[e];
        sl[e] = v;
        logits_out[t * NEXP + e] = v;
    }
    __syncthreads();
    if (tid == 0) {
        float v[NEXP];
#pragma unroll
        for (int i = 0; i < NEXP; ++i) v[i] = sl[i];
        int idx[TOPK]; float tv[TOPK];
        unsigned used = 0;
#pragma unroll
        for (int k = 0; k < TOPK; ++k) {
            float best = -__builtin_inff(); int bi = 0;
#pragma unroll
            for (int i = 0; i < NEXP; ++i)
                if (!((used >> i) & 1u) && v[i] > best) { best = v[i]; bi = i; }
            used |= 1u << bi; idx[k] = bi; tv[k] = best;
        }
        float m = tv[0];
        float ex[TOPK], s = 0.f;
#pragma unroll
        for (int k = 0; k < TOPK; ++k) { ex[k] = expf(tv[k] - m); s += ex[k]; }
#pragma unroll
        for (int k = 0; k < TOPK; ++k) {
            float w = ex[k] / s;
            int slot = atomicAdd(&counts[idx[k]], 1);
            lists[idx[k] * T_TOK + slot] = t;
            wts[idx[k] * T_TOK + slot] = w;
        }
    }
}

// ---------------- Kernel 2: exclusive prefix sum ---------------------------
__global__ void offsets_kernel(const int* __restrict__ counts, int* __restrict__ offsets)
{
    if (threadIdx.x == 0) {
        int o = 0;
        for (int e = 0; e < NEXP; ++e) { offsets[e] = o; o += counts[e]; }
        offsets[NEXP] = o;
    }
}

// ---------------- Kernel 3: gate_up GEMM + silu ----------------------------
// BM=128 gathered tokens, B rows = 64 gate cols + 64 up cols, BK=64,
// 4 waves (2x2). mt in HIGH bits so early-exit blocks are a contiguous tail
// (uncorrelated with XCD round-robin). XOR-swizzled LDS (rule #21: swizzle
// global source unit + ds_read unit, linear global_load_lds dest).
__global__ __launch_bounds__(256) void gu_kernel(
    const unsigned short* __restrict__ xb, const unsigned short* __restrict__ gupb,
    const float* __restrict__ gub, const int* __restrict__ counts,
    const int* __restrict__ offsets, const int* __restrict__ lists,
    unsigned short* __restrict__ inter)
{
    int bid = blockIdx.x;
    int mt = bid / (NEXP * 45);       // HIGH bits: 0..7
    int t2 = bid % (NEXP * 45);
    int nt = t2 % 45;
    int e  = t2 / 45;
    int ne = counts[e];
    if (mt * 128 >= ne) return;

    int tid = threadIdx.x;
    int wave = tid >> 6, lane = tid & 63;
    int l16 = lane & 15, lq = lane >> 4;
    int wm = wave >> 1, wn = wave & 1;

    __shared__ int tokid[128];
    __shared__ unsigned short sm[16384];   // As[0..8191], Bs[8192..16383]; reused as float Cs
    unsigned short* As = sm;
    unsigned short* Bs = sm + 8192;

    if (tid < 128) {
        int slot = mt * 128 + tid;
        tokid[tid] = (slot < ne) ? lists[e * T_TOK + slot] : lists[e * T_TOK];
    }
    __syncthreads();

    // source 16B-unit, XOR-swizzled by row&7 (row = tid>>3 within each s-stripe)
    int cE = (((tid & 7) ^ ((tid >> 3) & 7)) * 8);
    const unsigned short* gup_e = gupb + (size_t)e * GU_COLS * HDIM;
    const unsigned short* ab[4];
    const unsigned short* bb[4];
#pragma unroll
    for (int s = 0; s < 4; ++s) {
        int row = s * 32 + (tid >> 3);
        ab[s] = xb + (size_t)tokid[row] * HDIM + cE;
        int n = (row < 64) ? (nt * 64 + row) : (IDIM + nt * 64 + (row - 64));
        bb[s] = gup_e + (size_t)n * HDIM + cE;
    }

    f32x4 acc[4][4];
#pragma unroll
    for (int m = 0; m < 4; ++m)
#pragma unroll
        for (int n = 0; n < 4; ++n) acc[m][n] = (f32x4){0.f, 0.f, 0.f, 0.f};

    int sw = (l16 & 7) * 8;            // read-side XOR (units of 8 ushorts)
    for (int kk = 0; kk < HDIM; kk += 64) {
        __syncthreads();
#pragma unroll
        for (int s = 0; s < 4; ++s) {
            gload16(ab[s] + kk, As + s * 2048 + tid * 8);
            gload16(bb[s] + kk, Bs + s * 2048 + tid * 8);
        }
        __syncthreads();
#pragma unroll
        for (int ks = 0; ks < 2; ++ks) {
            short8 a[4], b[4];
#pragma unroll
            for (int m = 0; m < 4; ++m)
                a[m] = *(const short8*)&As[(wm * 64 + m * 16 + l16) * 64 + (((ks * 32 + lq * 8)) ^ sw)];
#pragma unroll
            for (int n = 0; n < 4; ++n)
                b[n] = *(const short8*)&Bs[(wn * 64 + n * 16 + l16) * 64 + (((ks * 32 + lq * 8)) ^ sw)];
#pragma unroll
            for (int m = 0; m < 4; ++m)
#pragma unroll
                for (int n = 0; n < 4; ++n)
                    acc[m][n] = __builtin_amdgcn_mfma_f32_16x16x32_bf16(a[m], b[n], acc[m][n], 0, 0, 0);
        }
    }

    __syncthreads();
    float* Cs = (float*)sm;
    if (wn == 1) {
#pragma unroll
        for (int m = 0; m < 4; ++m)
#pragma unroll
            for (int n = 0; n < 4; ++n)
#pragma unroll
                for (int r = 0; r < 4; ++r)
                    Cs[(wm * 64 + m * 16 + lq * 4 + r) * 64 + n * 16 + l16] = acc[m][n][r];
    }
    __syncthreads();
    if (wn == 0) {
        int off = offsets[e];
        const float* gbe = gub + (size_t)e * GU_COLS;
#pragma unroll
        for (int n = 0; n < 4; ++n) {
            int col = n * 16 + l16;
            float bg = gbe[nt * 64 + col];
            float bu = gbe[IDIM + nt * 64 + col];
#pragma unroll
            for (int m = 0; m < 4; ++m)
#pragma unroll
                for (int r = 0; r < 4; ++r) {
                    int row = wm * 64 + m * 16 + lq * 4 + r;
                    int slot = mt * 128 + row;
                    if (slot < ne) {
                        float g = acc[m][n][r] + bg;
                        float u = Cs[row * 64 + col] + bu;
                        float sg = g / (1.f + expf(-g));
                        inter[(size_t)(off + slot) * IDIM + nt * 64 + col] = f2b(sg * u);
                    }
                }
        }
    }
}

// ---------------- Kernel 4: down GEMM + weighted scatter-add ---------------
__global__ __launch_bounds__(256) void down_kernel(
    const unsigned short* __restrict__ inter, const unsigned short* __restrict__ dwb,
    const float* __restrict__ db, const int* __restrict__ counts,
    const int* __restrict__ offsets, const int* __restrict__ lists,
    const float* __restrict__ wts, float* __restrict__ out)
{
    int bid = blockIdx.x;
    int mt = bid / (NEXP * 8);        // HIGH bits: 0..15
    int t2 = bid % (NEXP * 8);
    int nt = t2 & 7;
    int e  = t2 >> 3;
    int ne = counts[e];
    if (mt * 64 >= ne) return;

    int tid = threadIdx.x;
    int wave = tid >> 6, lane = tid & 63;
    int l16 = lane & 15, lq = lane >> 4;
    int wm = wave >> 1, wn = wave & 1;

    __shared__ int tokid[64];
    __shared__ float twt[64];
    __shared__ unsigned short As[64 * 64];
    __shared__ unsigned short Bs[128 * 64];

    int off = offsets[e];
    if (tid < 64) {
        int slot = mt * 64 + tid;
        tokid[tid] = (slot < ne) ? lists[e * T_TOK + slot] : -1;
        twt[tid]   = (slot < ne) ? wts[e * T_TOK + slot] : 0.f;
    }
    __syncthreads();

    int cE = (((tid & 7) ^ ((tid >> 3) & 7)) * 8);
    const unsigned short* ab[2];
    const unsigned short* bb[4];
    const unsigned short* dw_e = dwb + (size_t)e * HDIM * IDIM;
#pragma unroll
    for (int s = 0; s < 2; ++s) {
        int row = s * 32 + (tid >> 3);
        int slotr = mt * 64 + row; if (slotr >= ne) slotr = ne - 1;
        ab[s] = inter + (size_t)(off + slotr) * IDIM + cE;
    }
#pragma unroll
    for (int s = 0; s < 4; ++s) {
        int h = nt * 128 + s * 32 + (tid >> 3);
        bb[s] = dw_e + (size_t)h * IDIM + cE;
    }

    f32x4 acc[2][4];
#pragma unroll
    for (int m = 0; m < 2; ++m)
#pragma unroll
        for (int n = 0; n < 4; ++n) acc[m][n] = (f32x4){0.f, 0.f, 0.f, 0.f};

    int sw = (l16 & 7) * 8;
    for (int kk = 0; kk < IDIM; kk += 64) {
        __syncthreads();
#pragma unroll
        for (int s = 0; s < 2; ++s)
            gload16(ab[s] + kk, As + s * 2048 + tid * 8);
#pragma unroll
        for (int s = 0; s < 4; ++s)
            gload16(bb[s] + kk, Bs + s * 2048 + tid * 8);
        __syncthreads();
#pragma unroll
        for (int ks = 0; ks < 2; ++ks) {
            short8 a[2], b[4];
#pragma unroll
            for (int m = 0; m < 2; ++m)
                a[m] = *(const short8*)&As[(wm * 32 + m * 16 + l16) * 64 + ((ks * 32 + lq * 8) ^ sw)];
#pragma unroll
            for (int n = 0; n < 4; ++n)
                b[n] = *(const short8*)&Bs[(wn * 64 + n * 16 + l16) * 64 + ((ks * 32 + lq * 8) ^ sw)];
#pragma unroll
            for (int m = 0; m < 2; ++m)
#pragma unroll
                for (int n = 0; n < 4; ++n)
                    acc[m][n] = __builtin_amdgcn_mfma_f32_16x16x32_bf16(a[m], b[n], acc[m][n], 0, 0, 0);
        }
    }

    const float* db_e = db + (size_t)e * HDIM;
#pragma unroll
    for (int n = 0; n < 4; ++n) {
        int h = nt * 128 + wn * 64 + n * 16 + l16;
        float bias = db_e[h];
#pragma unroll
        for (int m = 0; m < 2; ++m)
#pragma unroll
            for (int r = 0; r < 4; ++r) {
                int slot = wm * 32 + m * 16 + lq * 4 + r;
                int tk = tokid[slot];
                if (tk >= 0)
                    atomicAdd(out + (size_t)tk * HDIM + h, twt[slot] * (acc[m][n][r] + bias));
            }
    }
}

// ---------------------------------------------------------------------------
extern "C" void kernel_launch(void* const* d_in, const int* in_sizes, int n_in,
                              void* d_out, int out_size, void* d_ws, size_t ws_size,
                              hipStream_t stream)
{
    const float* x   = (const float*)d_in[0];
    const float* gw  = (const float*)d_in[1];
    const float* gb  = (const float*)d_in[2];
    const float* gup = (const float*)d_in[3];
    const float* gub = (const float*)d_in[4];
    const float* dw  = (const float*)d_in[5];
    const float* db  = (const float*)d_in[6];

    float* out        = (float*)d_out;
    float* logits_out = out + (size_t)T_TOK * HDIM;

    char* ws = (char*)d_ws;
    int*   counts  = (int*)(ws + 0);
    int*   offsets = (int*)(ws + 256);
    int*   lists   = (int*)(ws + 512);                       // 64 KB
    float* wts     = (float*)(ws + 512 + 65536);             // 64 KB
    unsigned short* xb    = (unsigned short*)(ws + 131584);  // 2 MB
    unsigned short* inter = (unsigned short*)(ws + 2228736); // 23.6 MB
    unsigned short* gupb  = (unsigned short*)(ws + 25821696);// 188.7 MB
    unsigned short* dwb   = (unsigned short*)(ws + 214565376);// 94.4 MB

    hipMemsetAsync(out, 0, (size_t)T_TOK * HDIM * sizeof(float), stream);
    hipMemsetAsync(counts, 0, 64, stream);

    convert_tr_kernel<<<NEXP * 16 * 90, 256, 0, stream>>>(gup, gupb, HDIM, GU_COLS, 16, 90);
    convert_tr_kernel<<<NEXP * 45 * 16, 256, 0, stream>>>(dw,  dwb,  IDIM, HDIM,    45, 16);
    router_kernel<<<T_TOK, 256, 0, stream>>>(x, gw, gb, logits_out, counts, lists, wts, xb);
    offsets_kernel<<<1, 64, 0, stream>>>(counts, offsets);
    gu_kernel<<<8 * NEXP * 45, 256, 0, stream>>>(xb, gupb, gub, counts, offsets, lists, inter);
    down_kernel<<<16 * NEXP * 8, 256, 0, stream>>>(inter, dwb, db, counts, offsets, lists, wts, out);
}

// Round 4
// 329.597 us; speedup vs baseline: 3.8316x; 1.3071x over previous
//
#include <hip/hip_runtime.h>
#include <hip/hip_bf16.h>
#include <stdint.h>

#define T_TOK 1024
#define HDIM  1024
#define NEXP  16
#define IDIM  2880
#define GU_COLS (2*IDIM)   // 5760
#define TOPK  4

using short4v  = __attribute__((ext_vector_type(4))) short;
using short8   = __attribute__((ext_vector_type(8))) short;
using ushort4v = __attribute__((ext_vector_type(4))) unsigned short;
using f32x4    = __attribute__((ext_vector_type(4))) float;

__device__ __forceinline__ unsigned short f2b(float f) {
    union { float f; unsigned u; } x; x.f = f;
    unsigned r = x.u + 0x7FFFu + ((x.u >> 16) & 1u);  // RNE
    return (unsigned short)(r >> 16);
}

typedef const __attribute__((address_space(1))) unsigned int* gas1_t;
typedef __attribute__((address_space(3))) unsigned int* las3_t;
__device__ __forceinline__ void gload16(const void* g, void* l) {
    __builtin_amdgcn_global_load_lds((gas1_t)g, (las3_t)l, 16, 0, 0);
}

// ---------------- Kernel 1: router + x->bf16 + zero out ---------------------
__global__ __launch_bounds__(256) void router_kernel(
    const float* __restrict__ x, const float* __restrict__ gw,
    const float* __restrict__ gb, float* __restrict__ logits_out,
    int* __restrict__ counts, int* __restrict__ lists, float* __restrict__ wts,
    unsigned short* __restrict__ xb, float* __restrict__ out)
{
    int t = blockIdx.x;
    int tid = threadIdx.x;
    const float* xr = x + (size_t)t * HDIM;
    {   // x -> bf16, and zero out row t
        float4 v = *(const float4*)(xr + tid * 4);
        ushort4v b; b.x = f2b(v.x); b.y = f2b(v.y); b.z = f2b(v.z); b.w = f2b(v.w);
        *(ushort4v*)(xb + (size_t)t * HDIM + tid * 4) = b;
        float4 z = make_float4(0.f, 0.f, 0.f, 0.f);
        *(float4*)(out + (size_t)t * HDIM + tid * 4) = z;
    }
    int e = tid >> 4;
    int l16 = tid & 15;
    const float* wr = gw + (size_t)e * HDIM;
    float p = 0.f;
    for (int h = l16; h < HDIM; h += 16) p += xr[h] * wr[h];
    p += __shfl_xor(p, 8);
    p += __shfl_xor(p, 4);
    p += __shfl_xor(p, 2);
    p += __shfl_xor(p, 1);
    __shared__ float sl[NEXP];
    if (l16 == 0) {
        float v = p + gb[e];
        sl[e] = v;
        logits_out[t * NEXP + e] = v;
    }
    __syncthreads();
    if (tid == 0) {
        float v[NEXP];
#pragma unroll
        for (int i = 0; i < NEXP; ++i) v[i] = sl[i];
        int idx[TOPK]; float tv[TOPK];
        unsigned used = 0;
#pragma unroll
        for (int k = 0; k < TOPK; ++k) {
            float best = -__builtin_inff(); int bi = 0;
#pragma unroll
            for (int i = 0; i < NEXP; ++i)
                if (!((used >> i) & 1u) && v[i] > best) { best = v[i]; bi = i; }
            used |= 1u << bi; idx[k] = bi; tv[k] = best;
        }
        float m = tv[0];
        float ex[TOPK], s = 0.f;
#pragma unroll
        for (int k = 0; k < TOPK; ++k) { ex[k] = expf(tv[k] - m); s += ex[k]; }
#pragma unroll
        for (int k = 0; k < TOPK; ++k) {
            float w = ex[k] / s;
            int slot = atomicAdd(&counts[idx[k]], 1);
            lists[idx[k] * T_TOK + slot] = t;
            wts[idx[k] * T_TOK + slot] = w;
        }
    }
}

// ---------------- Kernel 2: exclusive prefix sum ---------------------------
__global__ void offsets_kernel(const int* __restrict__ counts, int* __restrict__ offsets)
{
    if (threadIdx.x == 0) {
        int o = 0;
        for (int e = 0; e < NEXP; ++e) { offsets[e] = o; o += counts[e]; }
        offsets[NEXP] = o;
    }
}

// ---------------- Kernel 3: gate_up GEMM + silu (direct fp32 weights) ------
// BM=256 gathered tokens. B tile: 64 mixed rows = 32 gate cols + 32 up cols
// (same 32 output cols), BK=64, K=HDIM. 8 waves (8m x 1n): wave = 32m x 64n.
// A: xb bf16 via global_load_lds, linear dest + 16B-unit src/read XOR.
// B: fp32 -> bf16 reg-staged transpose, 8B-unit XOR slot = kb ^ (n&15).
// Intra-wave silu: gate frags {0,1} pair with up frags {2,3}.
__global__ __launch_bounds__(512) void gu_kernel(
    const unsigned short* __restrict__ xb, const float* __restrict__ gup,
    const float* __restrict__ gub, const int* __restrict__ counts,
    const int* __restrict__ offsets, const int* __restrict__ lists,
    unsigned short* __restrict__ inter)
{
    int bid = blockIdx.x;
    int nt = bid % 90;
    int t2 = bid / 90;
    int e  = t2 & 15;
    int mt = t2 >> 4;          // HIGH bits: 0..3
    int ne = counts[e];
    if (mt * 256 >= ne) return;

    int tid = threadIdx.x;
    int wave = tid >> 6, lane = tid & 63;
    int l16 = lane & 15, lq = lane >> 4;

    __shared__ int tokid[256];
    __shared__ unsigned short As[256 * 64];   // 32 KB
    __shared__ unsigned short Bs[64 * 64];    // 8 KB

    if (tid < 256) {
        int slot = mt * 256 + tid;
        tokid[tid] = (slot < ne) ? lists[e * T_TOK + slot] : lists[e * T_TOK];
    }
    __syncthreads();

    const float* gup_e = gup + (size_t)e * HDIM * GU_COLS;

    // A stagers: threads 256..511, 8 chunks each
    int at = tid - 256;
    const unsigned short* asrc[8];
    if (tid >= 256) {
#pragma unroll
        for (int i = 0; i < 8; ++i) {
            int s = at + i * 256;
            int row = s >> 3, c = s & 7;
            asrc[i] = xb + (size_t)tokid[row] * HDIM + ((c ^ (row & 7)) * 8);
        }
    }
    // B stagers: threads 0..255: nb = n-block(4), kb = k-chunk(4)
    int nb = tid & 15, kb = tid >> 4;
    const float* bsrc = nullptr;
    if (tid < 256) {
        int n0 = nb * 4;
        size_t col = (n0 < 32) ? (size_t)(nt * 32 + n0) : (size_t)(IDIM + nt * 32 + (n0 - 32));
        bsrc = gup_e + (size_t)(kb * 4) * GU_COLS + col;
    }

    f32x4 acc[2][4];
#pragma unroll
    for (int i = 0; i < 2; ++i)
#pragma unroll
        for (int f = 0; f < 4; ++f) acc[i][f] = (f32x4){0.f, 0.f, 0.f, 0.f};

    for (int kk = 0; kk < HDIM; kk += 64) {
        __syncthreads();
        if (tid >= 256) {
#pragma unroll
            for (int i = 0; i < 8; ++i)
                gload16(asrc[i] + kk, As + ((size_t)(at + i * 256)) * 8);
        } else {
            const float* sp = bsrc + (size_t)kk * GU_COLS;
            float4 r0 = *(const float4*)(sp);
            float4 r1 = *(const float4*)(sp + GU_COLS);
            float4 r2 = *(const float4*)(sp + 2 * GU_COLS);
            float4 r3 = *(const float4*)(sp + 3 * GU_COLS);
#pragma unroll
            for (int j = 0; j < 4; ++j) {
                int n = nb * 4 + j;
                int slot = kb ^ (n & 15);
                float e0 = (&r0.x)[j], e1 = (&r1.x)[j], e2 = (&r2.x)[j], e3 = (&r3.x)[j];
                ushort4v b; b.x = f2b(e0); b.y = f2b(e1); b.z = f2b(e2); b.w = f2b(e3);
                *(ushort4v*)&Bs[n * 64 + slot * 4] = b;
            }
        }
        __syncthreads();
#pragma unroll
        for (int ks = 0; ks < 2; ++ks) {
            short8 a[2], b[4];
#pragma unroll
            for (int i = 0; i < 2; ++i) {
                int row = wave * 32 + i * 16 + l16;
                int q = ks * 4 + lq;
                a[i] = *(const short8*)&As[row * 64 + ((q ^ (row & 7)) * 8)];
            }
#pragma unroll
            for (int f = 0; f < 4; ++f) {
                int n = f * 16 + l16;
                int u0 = (ks * 8 + lq * 2) ^ (n & 15);
                int u1 = (ks * 8 + lq * 2 + 1) ^ (n & 15);
                short4v h0 = *(const short4v*)&Bs[n * 64 + u0 * 4];
                short4v h1 = *(const short4v*)&Bs[n * 64 + u1 * 4];
                b[f] = __builtin_shufflevector(h0, h1, 0, 1, 2, 3, 4, 5, 6, 7);
            }
#pragma unroll
            for (int i = 0; i < 2; ++i)
#pragma unroll
                for (int f = 0; f < 4; ++f)
                    acc[i][f] = __builtin_amdgcn_mfma_f32_16x16x32_bf16(a[i], b[f], acc[i][f], 0, 0, 0);
        }
    }

    // ---- epilogue: intra-wave silu(gate)*up, write bf16 ----
    int off = offsets[e];
    const float* gbe = gub + (size_t)e * GU_COLS;
#pragma unroll
    for (int j = 0; j < 2; ++j) {
        int col = j * 16 + l16;                 // 0..31 within nt's 32 cols
        float bg = gbe[nt * 32 + col];
        float bu = gbe[IDIM + nt * 32 + col];
#pragma unroll
        for (int i = 0; i < 2; ++i)
#pragma unroll
            for (int r = 0; r < 4; ++r) {
                int row = wave * 32 + i * 16 + lq * 4 + r;
                int slot = mt * 256 + row;
                if (slot < ne) {
                    float g = acc[i][j][r] + bg;
                    float u = acc[i][j + 2][r] + bu;
                    float sg = g / (1.f + expf(-g));
                    inter[(size_t)(off + slot) * IDIM + nt * 32 + col] = f2b(sg * u);
                }
            }
    }
}

// ---------------- Kernel 4: down GEMM + weighted scatter (direct fp32) -----
// BM=256 slots, BN=64 h-cols, BK=64, K=IDIM. Same staging machinery as gu.
__global__ __launch_bounds__(512) void down_kernel(
    const unsigned short* __restrict__ inter, const float* __restrict__ dw,
    const float* __restrict__ db, const int* __restrict__ counts,
    const int* __restrict__ offsets, const int* __restrict__ lists,
    const float* __restrict__ wts, float* __restrict__ out)
{
    int bid = blockIdx.x;
    int ht = bid & 15;
    int t2 = bid >> 4;
    int e  = t2 & 15;
    int mt = t2 >> 4;          // HIGH bits: 0..3
    int ne = counts[e];
    if (mt * 256 >= ne) return;

    int tid = threadIdx.x;
    int wave = tid >> 6, lane = tid & 63;
    int l16 = lane & 15, lq = lane >> 4;

    __shared__ int tokid[256];
    __shared__ float twt[256];
    __shared__ unsigned short As[256 * 64];   // 32 KB
    __shared__ unsigned short Bs[64 * 64];    // 8 KB

    int off = offsets[e];
    if (tid < 256) {
        int slot = mt * 256 + tid;
        tokid[tid] = (slot < ne) ? lists[e * T_TOK + slot] : -1;
        twt[tid]   = (slot < ne) ? wts[e * T_TOK + slot] : 0.f;
    }
    __syncthreads();

    const float* dw_e = dw + (size_t)e * IDIM * HDIM;

    int at = tid - 256;
    const unsigned short* asrc[8];
    if (tid >= 256) {
#pragma unroll
        for (int i = 0; i < 8; ++i) {
            int s = at + i * 256;
            int row = s >> 3, c = s & 7;
            int slotr = mt * 256 + row; if (slotr >= ne) slotr = ne - 1;
            asrc[i] = inter + (size_t)(off + slotr) * IDIM + ((c ^ (row & 7)) * 8);
        }
    }
    int nb = tid & 15, kb = tid >> 4;
    const float* bsrc = nullptr;
    if (tid < 256)
        bsrc = dw_e + (size_t)(kb * 4) * HDIM + ht * 64 + nb * 4;

    f32x4 acc[2][4];
#pragma unroll
    for (int i = 0; i < 2; ++i)
#pragma unroll
        for (int f = 0; f < 4; ++f) acc[i][f] = (f32x4){0.f, 0.f, 0.f, 0.f};

    for (int kk = 0; kk < IDIM; kk += 64) {
        __syncthreads();
        if (tid >= 256) {
#pragma unroll
            for (int i = 0; i < 8; ++i)
                gload16(asrc[i] + kk, As + ((size_t)(at + i * 256)) * 8);
        } else {
            const float* sp = bsrc + (size_t)kk * HDIM;
            float4 r0 = *(const float4*)(sp);
            float4 r1 = *(const float4*)(sp + HDIM);
            float4 r2 = *(const float4*)(sp + 2 * HDIM);
            float4 r3 = *(const float4*)(sp + 3 * HDIM);
#pragma unroll
            for (int j = 0; j < 4; ++j) {
                int n = nb * 4 + j;
                int slot = kb ^ (n & 15);
                float e0 = (&r0.x)[j], e1 = (&r1.x)[j], e2 = (&r2.x)[j], e3 = (&r3.x)[j];
                ushort4v b; b.x = f2b(e0); b.y = f2b(e1); b.z = f2b(e2); b.w = f2b(e3);
                *(ushort4v*)&Bs[n * 64 + slot * 4] = b;
            }
        }
        __syncthreads();
#pragma unroll
        for (int ks = 0; ks < 2; ++ks) {
            short8 a[2], b[4];
#pragma unroll
            for (int i = 0; i < 2; ++i) {
                int row = wave * 32 + i * 16 + l16;
                int q = ks * 4 + lq;
                a[i] = *(const short8*)&As[row * 64 + ((q ^ (row & 7)) * 8)];
            }
#pragma unroll
            for (int f = 0; f < 4; ++f) {
                int n = f * 16 + l16;
                int u0 = (ks * 8 + lq * 2) ^ (n & 15);
                int u1 = (ks * 8 + lq * 2 + 1) ^ (n & 15);
                short4v h0 = *(const short4v*)&Bs[n * 64 + u0 * 4];
                short4v h1 = *(const short4v*)&Bs[n * 64 + u1 * 4];
                b[f] = __builtin_shufflevector(h0, h1, 0, 1, 2, 3, 4, 5, 6, 7);
            }
#pragma unroll
            for (int i = 0; i < 2; ++i)
#pragma unroll
                for (int f = 0; f < 4; ++f)
                    acc[i][f] = __builtin_amdgcn_mfma_f32_16x16x32_bf16(a[i], b[f], acc[i][f], 0, 0, 0);
        }
    }

    const float* db_e = db + (size_t)e * HDIM;
#pragma unroll
    for (int f = 0; f < 4; ++f) {
        int h = ht * 64 + f * 16 + l16;
        float bias = db_e[h];
#pragma unroll
        for (int i = 0; i < 2; ++i)
#pragma unroll
            for (int r = 0; r < 4; ++r) {
                int row = wave * 32 + i * 16 + lq * 4 + r;
                int tk = tokid[row];
                if (tk >= 0)
                    atomicAdd(out + (size_t)tk * HDIM + h, twt[row] * (acc[i][f][r] + bias));
            }
    }
}

// ---------------------------------------------------------------------------
extern "C" void kernel_launch(void* const* d_in, const int* in_sizes, int n_in,
                              void* d_out, int out_size, void* d_ws, size_t ws_size,
                              hipStream_t stream)
{
    const float* x   = (const float*)d_in[0];
    const float* gw  = (const float*)d_in[1];
    const float* gb  = (const float*)d_in[2];
    const float* gup = (const float*)d_in[3];
    const float* gub = (const float*)d_in[4];
    const float* dw  = (const float*)d_in[5];
    const float* db  = (const float*)d_in[6];

    float* out        = (float*)d_out;
    float* logits_out = out + (size_t)T_TOK * HDIM;

    char* ws = (char*)d_ws;
    int*   counts  = (int*)(ws + 0);
    int*   offsets = (int*)(ws + 256);
    int*   lists   = (int*)(ws + 512);                       // 64 KB
    float* wts     = (float*)(ws + 512 + 65536);             // 64 KB
    unsigned short* xb    = (unsigned short*)(ws + 131584);  // 2 MB
    unsigned short* inter = (unsigned short*)(ws + 2228736); // 23.6 MB

    hipMemsetAsync(counts, 0, 64, stream);

    router_kernel<<<T_TOK, 256, 0, stream>>>(x, gw, gb, logits_out, counts, lists, wts, xb, out);
    offsets_kernel<<<1, 64, 0, stream>>>(counts, offsets);
    gu_kernel<<<4 * NEXP * 90, 512, 0, stream>>>(xb, gup, gub, counts, offsets, lists, inter);
    down_kernel<<<4 * NEXP * 16, 512, 0, stream>>>(inter, dw, db, counts, offsets, lists, wts, out);
}

// Round 5
// 307.491 us; speedup vs baseline: 4.1071x; 1.0719x over previous
//
#include <hip/hip_runtime.h>
#include <hip/hip_bf16.h>
#include <stdint.h>

#define T_TOK 1024
#define HDIM  1024
#define NEXP  16
#define IDIM  2880
#define GU_COLS (2*IDIM)   // 5760
#define TOPK  4

using short4v  = __attribute__((ext_vector_type(4))) short;
using short8   = __attribute__((ext_vector_type(8))) short;
using ushort4v = __attribute__((ext_vector_type(4))) unsigned short;
using f32x4    = __attribute__((ext_vector_type(4))) float;

__device__ __forceinline__ unsigned short f2b(float f) {
    union { float f; unsigned u; } x; x.f = f;
    unsigned r = x.u + 0x7FFFu + ((x.u >> 16) & 1u);  // RNE
    return (unsigned short)(r >> 16);
}

typedef const __attribute__((address_space(1))) unsigned int* gas1_t;
typedef __attribute__((address_space(3))) unsigned int* las3_t;
__device__ __forceinline__ void gload16(const void* g, void* l) {
    __builtin_amdgcn_global_load_lds((gas1_t)g, (las3_t)l, 16, 0, 0);
}

// ---------------- Kernel 1: router + x->bf16 + zero out ---------------------
__global__ __launch_bounds__(256) void router_kernel(
    const float* __restrict__ x, const float* __restrict__ gw,
    const float* __restrict__ gb, float* __restrict__ logits_out,
    int* __restrict__ counts, int* __restrict__ lists, float* __restrict__ wts,
    unsigned short* __restrict__ xb, float* __restrict__ out)
{
    int t = blockIdx.x;
    int tid = threadIdx.x;
    const float* xr = x + (size_t)t * HDIM;
    {
        float4 v = *(const float4*)(xr + tid * 4);
        ushort4v b; b.x = f2b(v.x); b.y = f2b(v.y); b.z = f2b(v.z); b.w = f2b(v.w);
        *(ushort4v*)(xb + (size_t)t * HDIM + tid * 4) = b;
        float4 z = make_float4(0.f, 0.f, 0.f, 0.f);
        *(float4*)(out + (size_t)t * HDIM + tid * 4) = z;
    }
    int e = tid >> 4;
    int l16 = tid & 15;
    const float* wr = gw + (size_t)e * HDIM;
    float p = 0.f;
    for (int h = l16; h < HDIM; h += 16) p += xr[h] * wr[h];
    p += __shfl_xor(p, 8);
    p += __shfl_xor(p, 4);
    p += __shfl_xor(p, 2);
    p += __shfl_xor(p, 1);
    __shared__ float sl[NEXP];
    if (l16 == 0) {
        float v = p + gb[e];
        sl[e] = v;
        logits_out[t * NEXP + e] = v;
    }
    __syncthreads();
    if (tid == 0) {
        float v[NEXP];
#pragma unroll
        for (int i = 0; i < NEXP; ++i) v[i] = sl[i];
        int idx[TOPK]; float tv[TOPK];
        unsigned used = 0;
#pragma unroll
        for (int k = 0; k < TOPK; ++k) {
            float best = -__builtin_inff(); int bi = 0;
#pragma unroll
            for (int i = 0; i < NEXP; ++i)
                if (!((used >> i) & 1u) && v[i] > best) { best = v[i]; bi = i; }
            used |= 1u << bi; idx[k] = bi; tv[k] = best;
        }
        float m = tv[0];
        float ex[TOPK], s = 0.f;
#pragma unroll
        for (int k = 0; k < TOPK; ++k) { ex[k] = expf(tv[k] - m); s += ex[k]; }
#pragma unroll
        for (int k = 0; k < TOPK; ++k) {
            float w = ex[k] / s;
            int slot = atomicAdd(&counts[idx[k]], 1);
            lists[idx[k] * T_TOK + slot] = t;
            wts[idx[k] * T_TOK + slot] = w;
        }
    }
}

// ---------------- Kernel 2: exclusive prefix sum ---------------------------
__global__ void offsets_kernel(const int* __restrict__ counts, int* __restrict__ offsets)
{
    if (threadIdx.x == 0) {
        int o = 0;
        for (int e = 0; e < NEXP; ++e) { offsets[e] = o; o += counts[e]; }
        offsets[NEXP] = o;
    }
}

// ---------------- Kernel 3: gate_up GEMM + silu (direct fp32 weights) ------
// BM=256, B tile 64 mixed rows (32 gate + 32 up cols), BK=64. 8 waves.
// T14 async-split: B global loads for tile t+1 issued right after the
// compute-releasing barrier (hide under MFMA); convert+ds_write at next
// iteration top. A via global_load_lds (L2-resident xb).
__global__ __launch_bounds__(512) void gu_kernel(
    const unsigned short* __restrict__ xb, const float* __restrict__ gup,
    const float* __restrict__ gub, const int* __restrict__ counts,
    const int* __restrict__ offsets, const int* __restrict__ lists,
    unsigned short* __restrict__ inter)
{
    int bid = blockIdx.x;
    int nt = bid % 90;
    int t2 = bid / 90;
    int e  = t2 & 15;
    int mt = t2 >> 4;          // HIGH bits: 0..3
    int ne = counts[e];
    if (mt * 256 >= ne) return;

    int tid = threadIdx.x;
    int wave = tid >> 6, lane = tid & 63;
    int l16 = lane & 15, lq = lane >> 4;

    __shared__ int tokid[256];
    __shared__ unsigned short As[256 * 64];   // 32 KB
    __shared__ unsigned short Bs[64 * 64];    // 8 KB

    if (tid < 256) {
        int slot = mt * 256 + tid;
        tokid[tid] = (slot < ne) ? lists[e * T_TOK + slot] : lists[e * T_TOK];
    }
    __syncthreads();

    const float* gup_e = gup + (size_t)e * HDIM * GU_COLS;

    int at = tid - 256;
    const unsigned short* asrc[8];
    if (tid >= 256) {
#pragma unroll
        for (int i = 0; i < 8; ++i) {
            int s = at + i * 256;
            int row = s >> 3, c = s & 7;
            asrc[i] = xb + (size_t)tokid[row] * HDIM + ((c ^ (row & 7)) * 8);
        }
    }
    int nb = tid & 15, kb = tid >> 4;
    const float* bsrc = nullptr;
    if (tid < 256) {
        int n0 = nb * 4;
        size_t col = (n0 < 32) ? (size_t)(nt * 32 + n0) : (size_t)(IDIM + nt * 32 + (n0 - 32));
        bsrc = gup_e + (size_t)(kb * 4) * GU_COLS + col;
    }

    f32x4 acc[2][4];
#pragma unroll
    for (int i = 0; i < 2; ++i)
#pragma unroll
        for (int f = 0; f < 4; ++f) acc[i][f] = (f32x4){0.f, 0.f, 0.f, 0.f};

    // B prologue: tile 0 into regs
    float4 br0, br1, br2, br3;
    if (tid < 256) {
        br0 = *(const float4*)(bsrc);
        br1 = *(const float4*)(bsrc + GU_COLS);
        br2 = *(const float4*)(bsrc + 2 * GU_COLS);
        br3 = *(const float4*)(bsrc + 3 * GU_COLS);
    }

    for (int kk = 0; kk < HDIM; kk += 64) {
        __syncthreads();                       // LDS free (prev readers done)
        if (tid >= 256) {
#pragma unroll
            for (int i = 0; i < 8; ++i)
                gload16(asrc[i] + kk, As + ((size_t)(at + i * 256)) * 8);
        } else {
            // convert + write B tile kk from regs
#pragma unroll
            for (int j = 0; j < 4; ++j) {
                int n = nb * 4 + j;
                int slot = kb ^ (n & 15);
                ushort4v b;
                b.x = f2b((&br0.x)[j]); b.y = f2b((&br1.x)[j]);
                b.z = f2b((&br2.x)[j]); b.w = f2b((&br3.x)[j]);
                *(ushort4v*)&Bs[n * 64 + slot * 4] = b;
            }
        }
        __syncthreads();                       // drains vmcnt (A) + lgkm (B writes)
        // issue B loads for tile kk+64 — in flight during MFMA below
        if (tid < 256 && kk + 64 < HDIM) {
            const float* sp = bsrc + (size_t)(kk + 64) * GU_COLS;
            br0 = *(const float4*)(sp);
            br1 = *(const float4*)(sp + GU_COLS);
            br2 = *(const float4*)(sp + 2 * GU_COLS);
            br3 = *(const float4*)(sp + 3 * GU_COLS);
        }
#pragma unroll
        for (int ks = 0; ks < 2; ++ks) {
            short8 a[2], b[4];
#pragma unroll
            for (int i = 0; i < 2; ++i) {
                int row = wave * 32 + i * 16 + l16;
                int q = ks * 4 + lq;
                a[i] = *(const short8*)&As[row * 64 + ((q ^ (row & 7)) * 8)];
            }
#pragma unroll
            for (int f = 0; f < 4; ++f) {
                int n = f * 16 + l16;
                int u0 = (ks * 8 + lq * 2) ^ (n & 15);
                int u1 = (ks * 8 + lq * 2 + 1) ^ (n & 15);
                short4v h0 = *(const short4v*)&Bs[n * 64 + u0 * 4];
                short4v h1 = *(const short4v*)&Bs[n * 64 + u1 * 4];
                b[f] = __builtin_shufflevector(h0, h1, 0, 1, 2, 3, 4, 5, 6, 7);
            }
#pragma unroll
            for (int i = 0; i < 2; ++i)
#pragma unroll
                for (int f = 0; f < 4; ++f)
                    acc[i][f] = __builtin_amdgcn_mfma_f32_16x16x32_bf16(a[i], b[f], acc[i][f], 0, 0, 0);
        }
    }

    // ---- epilogue: intra-wave silu(gate)*up ----
    int off = offsets[e];
    const float* gbe = gub + (size_t)e * GU_COLS;
#pragma unroll
    for (int j = 0; j < 2; ++j) {
        int col = j * 16 + l16;
        float bg = gbe[nt * 32 + col];
        float bu = gbe[IDIM + nt * 32 + col];
#pragma unroll
        for (int i = 0; i < 2; ++i)
#pragma unroll
            for (int r = 0; r < 4; ++r) {
                int row = wave * 32 + i * 16 + lq * 4 + r;
                int slot = mt * 256 + row;
                if (slot < ne) {
                    float g = acc[i][j][r] + bg;
                    float u = acc[i][j + 2][r] + bu;
                    float sg = g / (1.f + expf(-g));
                    inter[(size_t)(off + slot) * IDIM + nt * 32 + col] = f2b(sg * u);
                }
            }
    }
}

// ---------------- Kernel 4: down GEMM + weighted scatter (direct fp32) -----
__global__ __launch_bounds__(512) void down_kernel(
    const unsigned short* __restrict__ inter, const float* __restrict__ dw,
    const float* __restrict__ db, const int* __restrict__ counts,
    const int* __restrict__ offsets, const int* __restrict__ lists,
    const float* __restrict__ wts, float* __restrict__ out)
{
    int bid = blockIdx.x;
    int ht = bid & 15;
    int t2 = bid >> 4;
    int e  = t2 & 15;
    int mt = t2 >> 4;          // HIGH bits: 0..3
    int ne = counts[e];
    if (mt * 256 >= ne) return;

    int tid = threadIdx.x;
    int wave = tid >> 6, lane = tid & 63;
    int l16 = lane & 15, lq = lane >> 4;

    __shared__ int tokid[256];
    __shared__ float twt[256];
    __shared__ unsigned short As[256 * 64];   // 32 KB
    __shared__ unsigned short Bs[64 * 64];    // 8 KB

    int off = offsets[e];
    if (tid < 256) {
        int slot = mt * 256 + tid;
        tokid[tid] = (slot < ne) ? lists[e * T_TOK + slot] : -1;
        twt[tid]   = (slot < ne) ? wts[e * T_TOK + slot] : 0.f;
    }
    __syncthreads();

    const float* dw_e = dw + (size_t)e * IDIM * HDIM;

    int at = tid - 256;
    const unsigned short* asrc[8];
    if (tid >= 256) {
#pragma unroll
        for (int i = 0; i < 8; ++i) {
            int s = at + i * 256;
            int row = s >> 3, c = s & 7;
            int slotr = mt * 256 + row; if (slotr >= ne) slotr = ne - 1;
            asrc[i] = inter + (size_t)(off + slotr) * IDIM + ((c ^ (row & 7)) * 8);
        }
    }
    int nb = tid & 15, kb = tid >> 4;
    const float* bsrc = nullptr;
    if (tid < 256)
        bsrc = dw_e + (size_t)(kb * 4) * HDIM + ht * 64 + nb * 4;

    f32x4 acc[2][4];
#pragma unroll
    for (int i = 0; i < 2; ++i)
#pragma unroll
        for (int f = 0; f < 4; ++f) acc[i][f] = (f32x4){0.f, 0.f, 0.f, 0.f};

    float4 br0, br1, br2, br3;
    if (tid < 256) {
        br0 = *(const float4*)(bsrc);
        br1 = *(const float4*)(bsrc + HDIM);
        br2 = *(const float4*)(bsrc + 2 * HDIM);
        br3 = *(const float4*)(bsrc + 3 * HDIM);
    }

    for (int kk = 0; kk < IDIM; kk += 64) {
        __syncthreads();
        if (tid >= 256) {
#pragma unroll
            for (int i = 0; i < 8; ++i)
                gload16(asrc[i] + kk, As + ((size_t)(at + i * 256)) * 8);
        } else {
#pragma unroll
            for (int j = 0; j < 4; ++j) {
                int n = nb * 4 + j;
                int slot = kb ^ (n & 15);
                ushort4v b;
                b.x = f2b((&br0.x)[j]); b.y = f2b((&br1.x)[j]);
                b.z = f2b((&br2.x)[j]); b.w = f2b((&br3.x)[j]);
                *(ushort4v*)&Bs[n * 64 + slot * 4] = b;
            }
        }
        __syncthreads();
        if (tid < 256 && kk + 64 < IDIM) {
            const float* sp = bsrc + (size_t)(kk + 64) * HDIM;
            br0 = *(const float4*)(sp);
            br1 = *(const float4*)(sp + HDIM);
            br2 = *(const float4*)(sp + 2 * HDIM);
            br3 = *(const float4*)(sp + 3 * HDIM);
        }
#pragma unroll
        for (int ks = 0; ks < 2; ++ks) {
            short8 a[2], b[4];
#pragma unroll
            for (int i = 0; i < 2; ++i) {
                int row = wave * 32 + i * 16 + l16;
                int q = ks * 4 + lq;
                a[i] = *(const short8*)&As[row * 64 + ((q ^ (row & 7)) * 8)];
            }
#pragma unroll
            for (int f = 0; f < 4; ++f) {
                int n = f * 16 + l16;
                int u0 = (ks * 8 + lq * 2) ^ (n & 15);
                int u1 = (ks * 8 + lq * 2 + 1) ^ (n & 15);
                short4v h0 = *(const short4v*)&Bs[n * 64 + u0 * 4];
                short4v h1 = *(const short4v*)&Bs[n * 64 + u1 * 4];
                b[f] = __builtin_shufflevector(h0, h1, 0, 1, 2, 3, 4, 5, 6, 7);
            }
#pragma unroll
            for (int i = 0; i < 2; ++i)
#pragma unroll
                for (int f = 0; f < 4; ++f)
                    acc[i][f] = __builtin_amdgcn_mfma_f32_16x16x32_bf16(a[i], b[f], acc[i][f], 0, 0, 0);
        }
    }

    const float* db_e = db + (size_t)e * HDIM;
#pragma unroll
    for (int f = 0; f < 4; ++f) {
        int h = ht * 64 + f * 16 + l16;
        float bias = db_e[h];
#pragma unroll
        for (int i = 0; i < 2; ++i)
#pragma unroll
            for (int r = 0; r < 4; ++r) {
                int row = wave * 32 + i * 16 + lq * 4 + r;
                int tk = tokid[row];
                if (tk >= 0)
                    atomicAdd(out + (size_t)tk * HDIM + h, twt[row] * (acc[i][f][r] + bias));
            }
    }
}

// ---------------------------------------------------------------------------
extern "C" void kernel_launch(void* const* d_in, const int* in_sizes, int n_in,
                              void* d_out, int out_size, void* d_ws, size_t ws_size,
                              hipStream_t stream)
{
    const float* x   = (const float*)d_in[0];
    const float* gw  = (const float*)d_in[1];
    const float* gb  = (const float*)d_in[2];
    const float* gup = (const float*)d_in[3];
    const float* gub = (const float*)d_in[4];
    const float* dw  = (const float*)d_in[5];
    const float* db  = (const float*)d_in[6];

    float* out        = (float*)d_out;
    float* logits_out = out + (size_t)T_TOK * HDIM;

    char* ws = (char*)d_ws;
    int*   counts  = (int*)(ws + 0);
    int*   offsets = (int*)(ws + 256);
    int*   lists   = (int*)(ws + 512);                       // 64 KB
    float* wts     = (float*)(ws + 512 + 65536);             // 64 KB
    unsigned short* xb    = (unsigned short*)(ws + 131584);  // 2 MB
    unsigned short* inter = (unsigned short*)(ws + 2228736); // 23.6 MB

    hipMemsetAsync(counts, 0, 64, stream);

    router_kernel<<<T_TOK, 256, 0, stream>>>(x, gw, gb, logits_out, counts, lists, wts, xb, out);
    offsets_kernel<<<1, 64, 0, stream>>>(counts, offsets);
    gu_kernel<<<4 * NEXP * 90, 512, 0, stream>>>(xb, gup, gub, counts, offsets, lists, inter);
    down_kernel<<<4 * NEXP * 16, 512, 0, stream>>>(inter, dw, db, counts, offsets, lists, wts, out);
}